// Round 5
// baseline (504.893 us; speedup 1.0000x reference)
//
#include <hip/hip_runtime.h>
#include <stdint.h>

// SpikingNeuralNetwork: B=32, S=4096, D=512, H=256, OUT=128
// out = broadcast_B( (1/S) * (Σ_s spikes[s,:]) @ W_h ), LIF scan over
// currents = x.mean(0) @ W_in.
//
// batch_mean: xmean[s][d] = (1/32) Σ_b x[b][s][d]. Pure HBM stream (268 MB),
//   2048 blocks × 256 thr, b-unrolled ×8 (8 coalesced 16B loads in flight).
//   Block 0 zeroes d_out for the scan's atomics.
// proj: currents^T = xmean @ W_in, stored transposed-by-4 (cur4[s/4][h]).
//   xmean addresses are wave-UNIFORM -> scalar s_load path (no LDS, this was
//   R4's 41 µs LDS-broadcast bottleneck); iw is the per-lane vector operand.
//   Inner expression grouping identical to R4 (absmax 0.0 preservation).
// snn_scan_out: LIF scan, 4 blocks × 64 lanes (1 wave/CU), one neuron chain
//   per lane. Chunks of 64 steps DMA'd via global_load_lds into a TRIPLE
//   buffer; drain via explicit s_waitcnt vmcnt(16) (imm 0x4F70) pinned with
//   sched_barrier(0): chunk c is guaranteed complete (FIFO vmcnt) while c+1
//   and c+2 remain in flight -> 2 chunk-scans of latency slack (R4's
//   __syncthreads drained vmcnt(0) with only ~1 chunk of slack).
//   Fused recurrence (bit-exact): u_s = sp1 ? 0 : fma(0.95, u, sp2 ? 0 : ic).

#define S_LEN 4096
#define D_DIM 512
#define H_DIM 256
#define O_DIM 128
#define B_SZ  32
#define CH    64                // scan steps per chunk
#define NCH   (S_LEN / CH)      // 64 chunks
#define ROWS  (CH / 4)          // 16 float4 rows per chunk

typedef const __attribute__((address_space(1))) void  glob_void;
typedef       __attribute__((address_space(3))) void  lds_void;

__global__ __launch_bounds__(256)
void batch_mean(const float4* __restrict__ x4,
                float4*       __restrict__ xm4,
                float*        __restrict__ out) {
    const int i = blockIdx.x * 256 + threadIdx.x;   // 0 .. S*D/4-1 exactly
    if (blockIdx.x == 0) {                          // zero out[] for scan atomics
        for (int k = threadIdx.x; k < B_SZ * O_DIM; k += 256) out[k] = 0.f;
    }
    const int SD4 = S_LEN * D_DIM / 4;
    const float4* p = x4 + i;
    float4 acc = make_float4(0.f, 0.f, 0.f, 0.f);
    for (int b = 0; b < B_SZ; b += 8) {
        float4 q[8];
        #pragma unroll
        for (int j = 0; j < 8; ++j) q[j] = p[(size_t)(b + j) * SD4];
        #pragma unroll                               // adds in ascending-b order
        for (int j = 0; j < 8; ++j) {
            acc.x += q[j].x; acc.y += q[j].y; acc.z += q[j].z; acc.w += q[j].w;
        }
    }
    const float inv = 1.0f / (float)B_SZ;
    acc.x *= inv; acc.y *= inv; acc.z *= inv; acc.w *= inv;
    xm4[i] = acc;
}

__global__ __launch_bounds__(256)
void proj(const float* __restrict__ xmean,
          const float* __restrict__ iw,
          float4*      __restrict__ cur4) {
    const int h  = threadIdx.x;                     // 256 h-columns
    const int s0 = blockIdx.x * 8;                  // 512 blocks x 8 s-rows
    float acc2[8];
    #pragma unroll
    for (int ss = 0; ss < 8; ++ss) acc2[ss] = 0.f;

    const float* xr = xmean + (size_t)s0 * D_DIM;
    for (int d = 0; d < D_DIM; d += 4) {
        float w0 = iw[(d + 0) * H_DIM + h];         // per-lane, coalesced, L2
        float w1 = iw[(d + 1) * H_DIM + h];
        float w2 = iw[(d + 2) * H_DIM + h];
        float w3 = iw[(d + 3) * H_DIM + h];
        #pragma unroll
        for (int ss = 0; ss < 8; ++ss) {
            const float* xp = xr + ss * D_DIM + d;  // wave-uniform -> s_load
            acc2[ss] += xp[0] * w0 + xp[1] * w1 + xp[2] * w2 + xp[3] * w3;
        }
    }
    // Transposed-by-4 store: cur4[(s0/4)+{0,1}][h]; lane h contiguous.
    const int g0 = (blockIdx.x * 2) * H_DIM + h;
    cur4[g0]         = make_float4(acc2[0], acc2[1], acc2[2], acc2[3]);
    cur4[g0 + H_DIM] = make_float4(acc2[4], acc2[5], acc2[6], acc2[7]);
}

// One LIF step, fused form (bit-exact to reference).
#define LIF_STEP(IC) {                          \
    float ict = sp2 ? 0.f : (IC);               \
    float tt  = fmaf(0.95f, u, ict);            \
    u   = sp1 ? 0.f : tt;                       \
    bool sp = (u >= 1.0f);                      \
    cnt += sp ? 1 : 0;                          \
    sp2 = sp1; sp1 = sp; }

__device__ __forceinline__ void stage_chunk(const float4* __restrict__ cur4,
                                            float4* dst, int c, int hbase, int lane) {
    #pragma unroll
    for (int r = 0; r < ROWS; ++r) {
        const float4* g = cur4 + (size_t)(c * ROWS + r) * H_DIM + hbase + lane;
        __builtin_amdgcn_global_load_lds((glob_void*)g,
                                         (lds_void*)&dst[r * 64 + lane], 16, 0, 0);
    }
}

__global__ __launch_bounds__(64)
void snn_scan_out(const float4* __restrict__ cur4,
                  const float*  __restrict__ hw,
                  float*        __restrict__ out) {
    __shared__ __attribute__((aligned(16))) float4 lbuf[3][ROWS * 64];  // 3 x 16 KB
    __shared__ float cl[64];
    const int lane  = threadIdx.x;              // one neuron chain per lane
    const int hbase = blockIdx.x * 64;          // 4 blocks cover h=0..255

    stage_chunk(cur4, lbuf[0], 0, hbase, lane);
    stage_chunk(cur4, lbuf[1], 1, hbase, lane);

    float u = 0.f;
    int   cnt = 0;
    bool  sp1 = false, sp2 = false;

    for (int c = 0; c < NCH; ++c) {
        if (c + 2 < NCH) {
            stage_chunk(cur4, lbuf[(c + 2) % 3], c + 2, hbase, lane);
            __builtin_amdgcn_sched_barrier(0);
            // vmcnt<=16 (imm: vm[3:0]=0,vm[5:4]=01<<14, exp=7, lgkm=0xF):
            // the 16 just-issued (c+2) may fly; FIFO => chunk c complete.
            __builtin_amdgcn_s_waitcnt(0x4F70);
            __builtin_amdgcn_sched_barrier(0);
        } else {
            __builtin_amdgcn_sched_barrier(0);
            __builtin_amdgcn_s_waitcnt(0x0F70);    // vmcnt(0): tail drain
            __builtin_amdgcn_sched_barrier(0);
        }

        const float4* lb = lbuf[c % 3];
        float4 v[ROWS];
        #pragma unroll
        for (int r = 0; r < ROWS; ++r) v[r] = lb[r * 64 + lane];
        __builtin_amdgcn_sched_barrier(0);      // reads must not sink into chain

        #pragma unroll
        for (int r = 0; r < ROWS; ++r) {
            LIF_STEP(v[r].x); LIF_STEP(v[r].y); LIF_STEP(v[r].z); LIF_STEP(v[r].w);
        }
    }

    // Epilogue: partial out_mean over this block's 64 neurons, atomic-combined.
    __syncthreads();
    cl[lane] = (float)cnt;
    __syncthreads();
    float a0 = 0.f, a1 = 0.f;
    #pragma unroll 8
    for (int k = 0; k < 64; ++k) {
        float c = cl[k];
        const float* w = hw + (size_t)(hbase + k) * O_DIM;
        a0 = fmaf(c, w[lane], a0);
        a1 = fmaf(c, w[lane + 64], a1);
    }
    a0 *= (1.0f / (float)S_LEN);
    a1 *= (1.0f / (float)S_LEN);
    for (int b = 0; b < B_SZ; ++b) {
        atomicAdd(out + b * O_DIM + lane,      a0);
        atomicAdd(out + b * O_DIM + lane + 64, a1);
    }
}

extern "C" void kernel_launch(void* const* d_in, const int* in_sizes, int n_in,
                              void* d_out, int out_size, void* d_ws, size_t ws_size,
                              hipStream_t stream) {
    const float4* x4 = (const float4*)d_in[0];       // [32,4096,512] f32
    const float*  iw = (const float*) d_in[1];       // [512,256] f32
    const float*  hw = (const float*) d_in[2];       // [256,128] f32
    float* out   = (float*)d_out;                    // [32,128] f32
    float4* cur4  = (float4*)d_ws;                   // [1024][256] float4 = 4 MB
    float4* xm4   = (float4*)((char*)d_ws + (size_t)4 * 1024 * 1024);  // 8 MB

    hipLaunchKernelGGL(batch_mean, dim3(S_LEN * D_DIM / 4 / 256), dim3(256), 0,
                       stream, x4, xm4, out);
    hipLaunchKernelGGL(proj, dim3(S_LEN / 8), dim3(256), 0, stream,
                       (const float*)xm4, iw, cur4);
    hipLaunchKernelGGL(snn_scan_out, dim3(4), dim3(64), 0, stream,
                       cur4, hw, out);
}